// Round 2
// baseline (164.459 us; speedup 1.0000x reference)
//
#include <hip/hip_runtime.h>
#include <stdint.h>

// ConvMemory fused: out[b,i,h,w] = (3x3 conv of E=exp(x), weights from memory) / boxsum(E)
// Reference pads x with ZEROS before softmax -> OOB taps contribute exp(0)=1
// to numerator and denominator; staging writes E=1 for OOB pixels which makes
// boundary handling automatic.

#define Cn 64
#define Hn 128
#define Wn 128
#define OC 128
#define HW (Hn * Wn)

typedef __attribute__((ext_vector_type(8))) short bf16x8_t;
typedef __attribute__((ext_vector_type(4))) float f32x4_t;
typedef __attribute__((ext_vector_type(16))) float f32x16_t;

__device__ inline unsigned short f2bf(float f) {
    union { float f; uint32_t u; } v; v.f = f;
    uint32_t u = v.u;
    u += 0x7fffu + ((u >> 16) & 1u);
    return (unsigned short)(u >> 16);
}
__device__ inline float bf2f(unsigned short h) {
    union { uint32_t u; float f; } v; v.u = ((uint32_t)h) << 16;
    return v.f;
}

// ---------------------------------------------------------------------------
// Kernel 1: reorder memory[576][128] -> Bt[n][k'] bf16, k' = (kh*3+kw)*64 + c
// ---------------------------------------------------------------------------
__global__ void prep_b(const float* __restrict__ mem, unsigned short* __restrict__ Bt) {
    int kin = blockIdx.x;   // 0..575  (= c*9 + q)
    int n = threadIdx.x;    // 0..127
    int c = kin / 9, q = kin % 9;
    Bt[n * 576 + q * 64 + c] = f2bf(mem[kin * OC + n]);
}

// ---------------------------------------------------------------------------
// Fused kernel: block = 16x16 output pixels. Stage exp(x) halo 18x18x64 bf16
// in LDS (XOR-swizzled), channel-sums S, Zinv, then implicit-GEMM conv with
// mfma_f32_32x32x16_bf16: M=256 (8 m-tiles of 32), N=128 (4 n-tiles of 32),
// K=576 (36 chunks of 16: fixed (kh,kw)=q, 16 channels). Wave owns 2 m-tiles
// x 4 n-tiles (acc = 128 VGPRs). B double-buffered from L2-resident Bt.
// ---------------------------------------------------------------------------
__global__ __launch_bounds__(256, 2) void fused_conv(const float* __restrict__ x,
                                                     const unsigned short* __restrict__ Bt,
                                                     float* __restrict__ out) {
    // Et layout: pixel p (0..323) * 72 shorts; channel c stored at
    // ((c>>4) ^ (p&3))*16 + (c&15)  (32B-granule XOR swizzle, breaks the
    // stride-144B bank pattern; 8-short k-chunks stay 16B-contiguous).
    __shared__ __align__(16) unsigned short Et[324 * 72];
    __shared__ __align__(16) float St[324];
    __shared__ __align__(16) float Zt[256];

    int bid = blockIdx.x;           // 512 = 8 b * 8 ty * 8 tx
    int b = bid >> 6;
    int ty = (bid >> 3) & 7, tx = bid & 7;
    int h0 = ty * 16, w0 = tx * 16;
    int t = threadIdx.x;

    const float* xb = x + (size_t)b * Cn * HW;

    // ---- stage halo: 324 pixels, thread covers p0=t and p1=t+256 ----
    int y0 = t / 18, x0 = t - y0 * 18;
    int p1 = t + 256;
    int y1 = p1 / 18, x1 = p1 - y1 * 18;
    bool v1 = (p1 < 324);
    int gy0 = h0 - 1 + y0, gx0 = w0 - 1 + x0;
    int gy1 = h0 - 1 + y1, gx1 = w0 - 1 + x1;
    bool in0 = (gy0 >= 0 && gy0 < Hn && gx0 >= 0 && gx0 < Wn);
    bool in1 = v1 && (gy1 >= 0 && gy1 < Hn && gx1 >= 0 && gx1 < Wn);
    int idx0 = in0 ? (gy0 * Wn + gx0) : 0;   // safe address even when OOB
    int idx1 = in1 ? (gy1 * Wn + gx1) : 0;
    int sw0 = t & 3, sw1 = p1 & 3;

    float s0 = 0.f, s1 = 0.f;
#pragma unroll 4
    for (int c = 0; c < 64; c++) {
        int cpos_hi = (c >> 4), cpos_lo = (c & 15);
        float va = xb[(size_t)c * HW + idx0];
        va = in0 ? va : 0.f;
        float ea = __expf(va);
        unsigned short ha = f2bf(ea);
        s0 += bf2f(ha);
        Et[t * 72 + (((cpos_hi ^ sw0) << 4) | cpos_lo)] = ha;
        if (v1) {
            float vb = xb[(size_t)c * HW + idx1];
            vb = in1 ? vb : 0.f;
            float eb = __expf(vb);
            unsigned short hb = f2bf(eb);
            s1 += bf2f(hb);
            Et[p1 * 72 + (((cpos_hi ^ sw1) << 4) | cpos_lo)] = hb;
        }
    }
    St[t] = s0;
    if (v1) St[p1] = s1;
    __syncthreads();

    // ---- Zinv per output pixel ----
    {
        int zy = t >> 4, zx = t & 15;
        float z = 0.f;
#pragma unroll
        for (int dy = 0; dy < 3; dy++)
#pragma unroll
            for (int dx = 0; dx < 3; dx++)
                z += St[(zy + dy) * 18 + (zx + dx)];
        Zt[t] = 1.0f / z;
    }
    __syncthreads();

    // ---- MFMA main loop ----
    int lane = t & 63;
    int wv = t >> 6;               // 0..3
    int m = lane & 31;             // A row (pixel within m-tile), B col (n)
    int hi = lane >> 5;            // k-half: k = hi*8 + j

    // pixel-row base for wave's two m-tiles: m-tile mtg = wv*2+i covers
    // tile rows y = mtg*2 + (m>>4), x = m&15
    int prb[2];
#pragma unroll
    for (int i = 0; i < 2; i++)
        prb[i] = (wv * 4 + i * 2 + (m >> 4)) * 18 + (m & 15);

    const unsigned short* bp[4];
#pragma unroll
    for (int nb = 0; nb < 4; nb++)
        bp[nb] = Bt + (size_t)(nb * 32 + m) * 576 + hi * 8;

    f32x16_t acc[2][4];
#pragma unroll
    for (int i = 0; i < 2; i++)
#pragma unroll
        for (int nb = 0; nb < 4; nb++)
#pragma unroll
            for (int r = 0; r < 16; r++) acc[i][nb][r] = 0.f;

    bf16x8_t Af[2][2], Bf[2][4];

    auto loadK = [&](int kc, bf16x8_t* Ad, bf16x8_t* Bd) {
        int q = kc >> 2;              // 0..8 = kh*3+kw   (uniform)
        int c0b = kc & 3;             // channel block 0..3 (c0 = c0b*16)
        int kh = q / 3, kw = q - kh * 3;
        int poff = kh * 18 + kw;
#pragma unroll
        for (int i = 0; i < 2; i++) {
            int pix = prb[i] + poff;
            int a16 = pix * 72 + (((c0b ^ (pix & 3)) << 4) | (hi * 8));
            Ad[i] = *(const bf16x8_t*)&Et[a16];
        }
        int boff = q * 64 + c0b * 16;
#pragma unroll
        for (int nb = 0; nb < 4; nb++)
            Bd[nb] = *(const bf16x8_t*)(bp[nb] + boff);
    };

    loadK(0, Af[0], Bf[0]);
#pragma unroll 2
    for (int kc = 0; kc < 36; kc++) {
        int cur = kc & 1, nxt = cur ^ 1;
        if (kc + 1 < 36) loadK(kc + 1, Af[nxt], Bf[nxt]);
#pragma unroll
        for (int i = 0; i < 2; i++)
#pragma unroll
            for (int nb = 0; nb < 4; nb++)
                acc[i][nb] = __builtin_amdgcn_mfma_f32_32x32x16_bf16(
                    Af[cur][i], Bf[cur][nb], acc[i][nb], 0, 0, 0);
    }

    // ---- epilogue: D col(n)=lane&31, row=(r&3)+8*(r>>2)+4*hi ----
#pragma unroll
    for (int i = 0; i < 2; i++) {
        int mtg = wv * 2 + i;
#pragma unroll
        for (int g = 0; g < 4; g++) {
            int poff = g * 8 + hi * 4;
            int p = mtg * 32 + poff;        // + j (j=0..3) all in same row
            int yy = p >> 4, xx = p & 15;
            f32x4_t zi = *(const f32x4_t*)&Zt[p];
            float* op = out + ((size_t)(b * OC + m) * HW + (h0 + yy) * Wn + (w0 + xx));
#pragma unroll
            for (int nb = 0; nb < 4; nb++) {
                f32x4_t v;
                v.x = acc[i][nb][g * 4 + 0] * zi.x;
                v.y = acc[i][nb][g * 4 + 1] * zi.y;
                v.z = acc[i][nb][g * 4 + 2] * zi.z;
                v.w = acc[i][nb][g * 4 + 3] * zi.w;
                *(f32x4_t*)(op + (size_t)nb * 32 * HW) = v;
            }
        }
    }
}

// ---------------------------------------------------------------------------
extern "C" void kernel_launch(void* const* d_in, const int* in_sizes, int n_in,
                              void* d_out, int out_size, void* d_ws, size_t ws_size,
                              hipStream_t stream) {
    const float* x = (const float*)d_in[0];
    const float* mem = (const float*)d_in[1];
    float* out = (float*)d_out;
    char* ws = (char*)d_ws;

    unsigned short* Bt = (unsigned short*)ws;   // 147,456 B

    prep_b<<<576, 128, 0, stream>>>(mem, Bt);
    fused_conv<<<512, 256, 0, stream>>>(x, Bt, out);
}

// Round 3
// 123.436 us; speedup vs baseline: 1.3323x; 1.3323x over previous
//
#include <hip/hip_runtime.h>
#include <stdint.h>

// ConvMemory: out = (3x3 conv of E=exp(x), weights=memory) / (3x3 boxsum of channel-sum(E))
// Zero-padding before softmax => OOB taps contribute exp(0)=1 to num & denom.
// Phase A: NCHW f32 -> NHWC bf16 Et + per-pixel channel sum S (coalesced both ways).
// Phase B: implicit-GEMM conv, mfma_f32_32x32x16_bf16, XOR-swizzled LDS halo,
//          pre-swizzled B chunks, fused Zinv epilogue.

#define Cn 64
#define Hn 128
#define Wn 128
#define OC 128
#define HW (Hn * Wn)

typedef __attribute__((ext_vector_type(8))) short bf16x8_t;
typedef __attribute__((ext_vector_type(4))) float f32x4_t;
typedef __attribute__((ext_vector_type(16))) float f32x16_t;

__device__ inline unsigned short f2bf(float f) {
    union { float f; uint32_t u; } v; v.f = f;
    uint32_t u = v.u;
    u += 0x7fffu + ((u >> 16) & 1u);
    return (unsigned short)(u >> 16);
}
__device__ inline float bf2f(unsigned short h) {
    union { uint32_t u; float f; } v; v.u = ((uint32_t)h) << 16;
    return v.f;
}

// ---------------------------------------------------------------------------
// prep: memory[576][128] f32 -> Bt2 bf16 chunks: chunk cid=(kc*2+hi), 128 n's,
// 16B per n = 8 channels c = (kc&3)*16 + hi*8 + j, q = kc>>2 (kh*3+kw).
// Block 36 writes the 128B "ones page" (bf16 1.0) used for OOB halo pixels.
// ---------------------------------------------------------------------------
__global__ void prep_b2(const float* __restrict__ mem, uint4* __restrict__ Bt2,
                        uint4* __restrict__ ones) {
    if (blockIdx.x == 36) {
        if (threadIdx.x < 8)
            ones[threadIdx.x] = make_uint4(0x3F803F80u, 0x3F803F80u, 0x3F803F80u, 0x3F803F80u);
        return;
    }
    int u = blockIdx.x * 256 + threadIdx.x;   // 0..9215
    int n = u & 127;
    int cid = u >> 7;                         // 0..71
    int hi = cid & 1;
    int kc = cid >> 1;                        // 0..35
    int q = kc >> 2, cblk = kc & 3;
    unsigned short h8[8];
#pragma unroll
    for (int j = 0; j < 8; j++) {
        int c = cblk * 16 + hi * 8 + j;
        h8[j] = f2bf(mem[(c * 9 + q) * OC + n]);
    }
    Bt2[cid * 128 + n] = *(const uint4*)h8;
}

// ---------------------------------------------------------------------------
// Phase A: per (b,h) row. Wave reads whole channel rows (float2, 512B/instr),
// exp -> f32 LDS [64][130] (bank-stride 2, conflict-free), transpose out as
// bf16 NHWC (128B/pixel coalesced) + channel sums S.
// ---------------------------------------------------------------------------
__global__ __launch_bounds__(256) void exp_tr2(const float* __restrict__ x,
                                               uint4* __restrict__ Etu,
                                               float* __restrict__ S) {
    __shared__ float lf[64][130];
    int bid = blockIdx.x;            // 1024 = 8 b * 128 h
    int b = bid >> 7, h = bid & 127;
    int t = threadIdx.x;
    int wv = t >> 6, lane = t & 63;

    const float* xr = x + (size_t)b * Cn * HW + h * Wn;
#pragma unroll
    for (int i = 0; i < 16; i++) {
        int c = i * 4 + wv;
        float2 v = *(const float2*)(xr + (size_t)c * HW + lane * 2);
        lf[c][2 * lane + 0] = __expf(v.x);
        lf[c][2 * lane + 1] = __expf(v.y);
    }
    __syncthreads();

    int w = t >> 1, ch0 = (t & 1) * 32;
    unsigned short us[32];
    float s = 0.f;
#pragma unroll
    for (int j = 0; j < 32; j++) {
        unsigned short hb = f2bf(lf[ch0 + j][w]);
        us[j] = hb;
        s += bf2f(hb);          // sum the bf16-rounded values (consistency)
    }
    size_t pix = (size_t)(b * Hn + h) * Wn + w;
    uint4* dst = Etu + pix * 8 + (t & 1) * 4;
    const uint4* srcv = (const uint4*)us;
    dst[0] = srcv[0]; dst[1] = srcv[1]; dst[2] = srcv[2]; dst[3] = srcv[3];

    s += __shfl_xor(s, 1);
    if ((t & 1) == 0) S[pix] = s;
}

// ---------------------------------------------------------------------------
// Phase B: 512 threads, 16x16 output tile (M=256, N=128). Halo 18x18 pixels
// bf16 in LDS, XOR-granule swizzle: pixel p, 16B-granule g stored at slot
// g^(p&7). Wave wv = m-tile (32 pixels); 4 n-tiles each; acc 4x f32x16.
// K-loop: 36 chunks of K=16 (q=kc>>2, cblk=kc&3), prefetch-1 pipeline.
// Zinv from S-halo box-sum in LDS; fused scale in epilogue.
// ---------------------------------------------------------------------------
__global__ __launch_bounds__(512, 2) void conv2(const uint4* __restrict__ Etu,
                                                const uint4* __restrict__ Bt2,
                                                const float* __restrict__ S,
                                                const uint4* __restrict__ ones,
                                                float* __restrict__ out) {
    __shared__ __align__(16) uint4 EtL[324 * 8];   // 41472 B
    __shared__ float Sh[324];
    __shared__ __align__(16) float Zt[256];

    int bid = blockIdx.x;            // 512 = 8 b * 8 ty * 8 tx
    int b = bid >> 6;
    int ty = (bid >> 3) & 7, tx = bid & 7;
    int h0 = ty * 16, w0 = tx * 16;
    int t = threadIdx.x;

    // ---- stage Et halo (324 pixels x 8 granules) ----
    const uint4* Etb = Etu + (size_t)b * HW * 8;
#pragma unroll
    for (int i = 0; i < 6; i++) {
        int qd = i * 512 + t;
        if (qd < 2592) {
            int p = qd >> 3, sslot = qd & 7;
            int py = p / 18, px = p - py * 18;
            int gy = h0 - 1 + py, gx = w0 - 1 + px;
            bool in = (gy >= 0) & (gy < Hn) & (gx >= 0) & (gx < Wn);
            int g = sslot ^ (p & 7);
            const uint4* src = in ? (Etb + ((size_t)(gy * Wn + gx)) * 8 + g)
                                  : (ones + g);
            EtL[p * 8 + sslot] = *src;
        }
    }
    // ---- stage S halo ----
    if (t < 324) {
        int py = t / 18, px = t - py * 18;
        int gy = h0 - 1 + py, gx = w0 - 1 + px;
        bool in = (gy >= 0) & (gy < Hn) & (gx >= 0) & (gx < Wn);
        Sh[t] = in ? S[(size_t)b * HW + gy * Wn + gx] : 64.0f;
    }
    __syncthreads();

    // ---- Zinv per output pixel ----
    if (t < 256) {
        int zy = t >> 4, zx = t & 15;
        float z = 0.f;
#pragma unroll
        for (int dy = 0; dy < 3; dy++)
#pragma unroll
            for (int dx = 0; dx < 3; dx++)
                z += Sh[(zy + dy) * 18 + (zx + dx)];
        Zt[t] = 1.0f / z;
    }
    __syncthreads();

    // ---- MFMA K-loop ----
    int lane = t & 63, wv = t >> 6;        // wv = m-tile 0..7
    int row = lane & 31, hi = lane >> 5;
    int py0 = wv * 2 + (row >> 4);         // tile y of this lane's pixel
    int px0 = row & 15;

    f32x16_t acc[4];
#pragma unroll
    for (int nb = 0; nb < 4; nb++)
#pragma unroll
        for (int r = 0; r < 16; r++) acc[nb][r] = 0.f;

    bf16x8_t Af[2];
    bf16x8_t Bf[2][4];

    auto loadK = [&](int kc, bf16x8_t& Ad, bf16x8_t* Bd) {
        int q = kc >> 2, cblk = kc & 3;
        int kh = q / 3, kw = q - kh * 3;
        int pix = (py0 + kh) * 18 + (px0 + kw);
        int g = cblk * 2 + hi;
        Ad = *(const bf16x8_t*)&EtL[pix * 8 + (g ^ (pix & 7))];
        const uint4* bp = Bt2 + (size_t)(kc * 2 + hi) * 128 + row;
#pragma unroll
        for (int nb = 0; nb < 4; nb++)
            Bd[nb] = *(const bf16x8_t*)(bp + nb * 32);
    };

    loadK(0, Af[0], Bf[0]);
#pragma unroll 2
    for (int kc = 0; kc < 36; kc++) {
        int cur = kc & 1, nxt = cur ^ 1;
        if (kc + 1 < 36) loadK(kc + 1, Af[nxt], Bf[nxt]);
#pragma unroll
        for (int nb = 0; nb < 4; nb++)
            acc[nb] = __builtin_amdgcn_mfma_f32_32x32x16_bf16(Af[cur], Bf[cur][nb], acc[nb], 0, 0, 0);
    }

    // ---- epilogue: D col n = lane&31, row r -> (r&3) + 8*(r>>2) + 4*hi ----
#pragma unroll
    for (int g4 = 0; g4 < 4; g4++) {
        int rowbase = g4 * 8 + hi * 4;
        int p = wv * 32 + rowbase;          // pixel; +j (0..3) same y
        int yy = p >> 4, xx = p & 15;
        f32x4_t zi = *(const f32x4_t*)&Zt[p];
#pragma unroll
        for (int nb = 0; nb < 4; nb++) {
            int n = nb * 32 + row;
            f32x4_t v;
            v.x = acc[nb][g4 * 4 + 0] * zi.x;
            v.y = acc[nb][g4 * 4 + 1] * zi.y;
            v.z = acc[nb][g4 * 4 + 2] * zi.z;
            v.w = acc[nb][g4 * 4 + 3] * zi.w;
            *(f32x4_t*)(out + ((size_t)(b * OC + n) * HW + (h0 + yy) * Wn + (w0 + xx))) = v;
        }
    }
}

// ---------------------------------------------------------------------------
extern "C" void kernel_launch(void* const* d_in, const int* in_sizes, int n_in,
                              void* d_out, int out_size, void* d_ws, size_t ws_size,
                              hipStream_t stream) {
    const float* x = (const float*)d_in[0];
    const float* mem = (const float*)d_in[1];
    float* out = (float*)d_out;
    char* ws = (char*)d_ws;

    uint4* Etu = (uint4*)ws;                               // 16,777,216 B
    float* S = (float*)(ws + 16777216);                    //    524,288 B
    uint4* Bt2 = (uint4*)(ws + 17301504);                  //    147,456 B
    uint4* ones = (uint4*)(ws + 17448960);                 //        128 B

    prep_b2<<<37, 256, 0, stream>>>(mem, Bt2, ones);
    exp_tr2<<<1024, 256, 0, stream>>>(x, Etu, S);
    conv2<<<512, 512, 0, stream>>>(Etu, Bt2, S, ones, out);
}